// Round 1
// baseline (707.391 us; speedup 1.0000x reference)
//
#include <hip/hip_runtime.h>

typedef float  f32x4 __attribute__((ext_vector_type(4)));
typedef short  s16x8 __attribute__((ext_vector_type(8)));
typedef unsigned short u16x4 __attribute__((ext_vector_type(4)));

#define MFMA16(a,b,c) __builtin_amdgcn_mfma_f32_16x16x32_bf16(a,b,c,0,0,0)

// sizes: B=128, S=20, T=19, E=H=512, G=2048, V=10000 (padded 10112)
#define PRED_ELEMS 24320000ull

__device__ __forceinline__ unsigned short f2bf(float f){
  unsigned u = __builtin_bit_cast(unsigned, f);
  u += 0x7fffu + ((u >> 16) & 1u);
  return (unsigned short)(u >> 16);
}
__device__ __forceinline__ float sigf(float x){ return 1.0f/(1.0f + __expf(-x)); }
__device__ __forceinline__ float tanh_(float x){
  x = fminf(15.0f, fmaxf(-15.0f, x));
  float e = __expf(2.0f*x);
  return (e - 1.0f) / (e + 1.0f);
}
__device__ __forceinline__ s16x8 ld8(const unsigned short* p){
  return *reinterpret_cast<const s16x8*>(p);
}

// ---------------- K0: stable descending sort by length, int outputs ----------------
__global__ void k0_sort(const int* __restrict__ length, const int* __restrict__ captions,
                        float* __restrict__ out, int* __restrict__ sortp,
                        int* __restrict__ declenp, int* __restrict__ nactp)
{
  __shared__ int sl[128], sdl[128], ssi[128];
  int tid = threadIdx.x;
  if (tid < 128) sl[tid] = length[tid];
  __syncthreads();
  if (tid < 128){
    int l = sl[tid];
    int rank = 0;
    for (int j = 0; j < 128; ++j){
      int lj = sl[j];
      rank += (lj > l) || (lj == l && j < tid);
    }
    sortp[rank] = tid; declenp[rank] = l - 1;
    ssi[rank] = tid;   sdl[rank] = l - 1;
  }
  __syncthreads();
  if (tid < 20){
    int c = 0;
    for (int r = 0; r < 128; ++r) c += (sdl[r] >= tid);
    nactp[tid] = c;
  }
  if (tid < 128){
    const size_t P = PRED_ELEMS;
    int si = ssi[tid];
    for (int t = 0; t < 20; ++t) out[P + tid*20 + t] = (float)captions[si*20 + t];
    out[P + 2560 + tid] = (float)sdl[tid];
    out[P + 2688 + tid] = (float)si;
  }
}

// ---------------- K1: bf16 conversion / gather / zero-init (4-elem units) ----------------
__device__ __forceinline__ void cvt4(unsigned short* dst, const float* src, int u){
  f32x4 v = *reinterpret_cast<const f32x4*>(src + (size_t)u*4);
  u16x4 o;
  o[0]=f2bf(v[0]); o[1]=f2bf(v[1]); o[2]=f2bf(v[2]); o[3]=f2bf(v[3]);
  *reinterpret_cast<u16x4*>(dst + (size_t)u*4) = o;
}

__global__ void k1_convert(const float* __restrict__ images, const int* __restrict__ captions,
    const float* __restrict__ emb, const float* __restrict__ wih, const float* __restrict__ whh,
    const float* __restrict__ bih, const float* __restrict__ bhh, const float* __restrict__ fcw,
    const int* __restrict__ sortp,
    unsigned short* __restrict__ wihb, unsigned short* __restrict__ whhb,
    unsigned short* __restrict__ fcwb, float* __restrict__ biasp,
    unsigned short* __restrict__ xseq, unsigned short* __restrict__ hbuf,
    float* __restrict__ cbuf)
{
  const int U0 = 262144;      // W_ih  2048*512/4
  const int U1 = 262144;      // W_hh
  const int U2 = 1294336;     // fc_w padded 10112*512/4
  const int U3 = 512;         // bias 2048/4
  const int U4 = 327680;      // xseq 20*128*512/4
  const int U5 = 32768;       // hbuf 2*128*512/4
  const int U6 = 16384;       // cbuf 128*512/4
  const int total = U0+U1+U2+U3+U4+U5+U6;
  for (int i = blockIdx.x*blockDim.x + threadIdx.x; i < total; i += gridDim.x*blockDim.x){
    int j = i;
    if (j < U0){ cvt4(wihb, wih, j); continue; }
    j -= U0;
    if (j < U1){ cvt4(whhb, whh, j); continue; }
    j -= U1;
    if (j < U2){
      int row = j >> 7;               // (j*4)/512
      if (row < 10000) cvt4(fcwb, fcw, j);
      else { u16x4 z = {0,0,0,0}; *reinterpret_cast<u16x4*>(fcwb + (size_t)j*4) = z; }
      continue;
    }
    j -= U2;
    if (j < U3){
      int e0 = j*4;
      for (int e = 0; e < 4; ++e) biasp[e0+e] = bih[e0+e] + bhh[e0+e];
      continue;
    }
    j -= U3;
    if (j < U4){
      int elem = j*4;
      int s = elem >> 16;             // /65536
      int rem = elem & 65535;
      int r = rem >> 9;
      int k = rem & 511;
      const float* src;
      if (s == 0) src = images + (size_t)sortp[r]*512 + k;
      else {
        int cap = captions[sortp[r]*20 + (s-1)];
        src = emb + (size_t)cap*512 + k;
      }
      f32x4 v = *reinterpret_cast<const f32x4*>(src);
      u16x4 o;
      o[0]=f2bf(v[0]); o[1]=f2bf(v[1]); o[2]=f2bf(v[2]); o[3]=f2bf(v[3]);
      *reinterpret_cast<u16x4*>(xseq + (size_t)j*4) = o;
      continue;
    }
    j -= U4;
    if (j < U5){ u16x4 z = {0,0,0,0}; *reinterpret_cast<u16x4*>(hbuf + (size_t)j*4) = z; continue; }
    j -= U5;
    { f32x4 z = {0.f,0.f,0.f,0.f}; *reinterpret_cast<f32x4*>(cbuf + (size_t)j*4) = z; }
  }
}

// ---------------- step kernel: LSTM call s (blocks 0..31) + FC for t=s-2 (blocks 32..347) ----------------
__global__ __launch_bounds__(256) void step_kernel(int s,
    const unsigned short* __restrict__ xseq, const unsigned short* __restrict__ wih,
    const unsigned short* __restrict__ whh, const unsigned short* __restrict__ fcwb,
    const float* __restrict__ bias, const float* __restrict__ fcb,
    unsigned short* __restrict__ hbuf, float* __restrict__ cbuf,
    const int* __restrict__ nact, float* __restrict__ out)
{
  const int lane = threadIdx.x & 63;
  const int wv   = threadIdx.x >> 6;
  const int fr   = lane & 15;
  const int fk   = (lane >> 4) * 8;

  if (blockIdx.x < 32){
    // ---------- LSTM gates GEMM + cell update ----------
    if (s > 19) return;
    __shared__ float lg[4][32][65];
    int rb = blockIdx.x >> 3, cb = blockIdx.x & 7;
    int row0 = rb*32, col0 = cb*64;
    if (row0 >= nact[s]) return;

    const unsigned short* xs = xseq + (size_t)s*65536;
    const unsigned short* hp = hbuf + (size_t)((s+1)&1)*65536;
    unsigned short*       hc = hbuf + (size_t)(s&1)*65536;

    const int q = wv;  // gate quadrant: 0=i 1=f 2=g 3=o
    f32x4 acc[2][4];
    for (int mt = 0; mt < 2; ++mt)
      for (int nt = 0; nt < 4; ++nt)
        acc[mt][nt] = (f32x4){0.f,0.f,0.f,0.f};

    #pragma unroll 4
    for (int k0 = 0; k0 < 1024; k0 += 32){
      const unsigned short* asrc; const unsigned short* wb; int kk;
      if (k0 < 512){ asrc = xs; wb = wih; kk = k0; }
      else         { asrc = hp; wb = whh; kk = k0 - 512; }
      s16x8 a0 = ld8(asrc + (row0      + fr)*512 + kk + fk);
      s16x8 a1 = ld8(asrc + (row0 + 16 + fr)*512 + kk + fk);
      int g0 = q*512 + col0 + fr;
      s16x8 b0 = ld8(wb + (g0     )*512 + kk + fk);
      s16x8 b1 = ld8(wb + (g0 + 16)*512 + kk + fk);
      s16x8 b2 = ld8(wb + (g0 + 32)*512 + kk + fk);
      s16x8 b3 = ld8(wb + (g0 + 48)*512 + kk + fk);
      acc[0][0] = MFMA16(a0, b0, acc[0][0]);
      acc[0][1] = MFMA16(a0, b1, acc[0][1]);
      acc[0][2] = MFMA16(a0, b2, acc[0][2]);
      acc[0][3] = MFMA16(a0, b3, acc[0][3]);
      acc[1][0] = MFMA16(a1, b0, acc[1][0]);
      acc[1][1] = MFMA16(a1, b1, acc[1][1]);
      acc[1][2] = MFMA16(a1, b2, acc[1][2]);
      acc[1][3] = MFMA16(a1, b3, acc[1][3]);
    }

    int rr = (lane >> 4) * 4;
    for (int mt = 0; mt < 2; ++mt)
      for (int nt = 0; nt < 4; ++nt)
        for (int p = 0; p < 4; ++p)
          lg[q][mt*16 + rr + p][nt*16 + fr] = acc[mt][nt][p];
    __syncthreads();

    int r  = threadIdx.x >> 3;
    int c8 = (threadIdx.x & 7) * 8;
    for (int jj = 0; jj < 8; ++jj){
      int c = c8 + jj, gj = col0 + c;
      float iv = lg[0][r][c] + bias[       gj];
      float fv = lg[1][r][c] + bias[ 512 + gj];
      float gv = lg[2][r][c] + bias[1024 + gj];
      float ov = lg[3][r][c] + bias[1536 + gj];
      int idx = (row0 + r)*512 + gj;
      float cn = sigf(fv)*cbuf[idx] + sigf(iv)*tanh_(gv);
      cbuf[idx] = cn;
      hc[idx] = f2bf(sigf(ov)*tanh_(cn));
    }
  } else {
    // ---------- FC for t = s-2, reading h_{s-1} ----------
    if (s < 2) return;
    int t  = s - 2;
    int fb = blockIdx.x - 32;
    int vb = fb >> 2, rt = fb & 3;
    int v0 = vb*128, row0 = rt*32;
    int n_t = nact[s-1];

    if (row0 >= n_t){
      int r = row0 + (threadIdx.x >> 3);
      int vb16 = v0 + (threadIdx.x & 7)*16;
      float* o = out + (size_t)(r*19 + t)*10000;
      f32x4 z = {0.f,0.f,0.f,0.f};
      for (int q4 = 0; q4 < 16; q4 += 4){
        int v = vb16 + q4;
        if (v < 10000) *reinterpret_cast<f32x4*>(o + v) = z;
      }
      return;
    }

    const unsigned short* hp = hbuf + (size_t)((s+1)&1)*65536;  // h_{s-1}
    int vw = v0 + wv*32;
    f32x4 acc[2][2];
    acc[0][0]=(f32x4){0.f,0.f,0.f,0.f}; acc[0][1]=(f32x4){0.f,0.f,0.f,0.f};
    acc[1][0]=(f32x4){0.f,0.f,0.f,0.f}; acc[1][1]=(f32x4){0.f,0.f,0.f,0.f};

    #pragma unroll 4
    for (int k0 = 0; k0 < 512; k0 += 32){
      s16x8 a0 = ld8(hp + (row0      + fr)*512 + k0 + fk);
      s16x8 a1 = ld8(hp + (row0 + 16 + fr)*512 + k0 + fk);
      s16x8 b0 = ld8(fcwb + (size_t)(vw      + fr)*512 + k0 + fk);
      s16x8 b1 = ld8(fcwb + (size_t)(vw + 16 + fr)*512 + k0 + fk);
      acc[0][0] = MFMA16(a0, b0, acc[0][0]);
      acc[0][1] = MFMA16(a0, b1, acc[0][1]);
      acc[1][0] = MFMA16(a1, b0, acc[1][0]);
      acc[1][1] = MFMA16(a1, b1, acc[1][1]);
    }

    int rr = (lane >> 4) * 4;
    for (int mt = 0; mt < 2; ++mt)
      for (int nt = 0; nt < 2; ++nt){
        int vv = vw + nt*16 + fr;
        if (vv < 10000){
          float bb = fcb[vv];
          for (int p = 0; p < 4; ++p){
            int r = row0 + mt*16 + rr + p;
            out[(size_t)(r*19 + t)*10000 + vv] = (r < n_t) ? (acc[mt][nt][p] + bb) : 0.0f;
          }
        }
      }
  }
}

extern "C" void kernel_launch(void* const* d_in, const int* in_sizes, int n_in,
                              void* d_out, int out_size, void* d_ws, size_t ws_size,
                              hipStream_t stream) {
  const float* images   = (const float*)d_in[0];
  const int*   captions = (const int*)  d_in[1];
  const int*   length   = (const int*)  d_in[2];
  const float* emb      = (const float*)d_in[3];
  const float* W_ih     = (const float*)d_in[4];
  const float* W_hh     = (const float*)d_in[5];
  const float* b_ih     = (const float*)d_in[6];
  const float* b_hh     = (const float*)d_in[7];
  const float* fc_w     = (const float*)d_in[8];
  const float* fc_b     = (const float*)d_in[9];
  float* out = (float*)d_out;
  char*  ws  = (char*)d_ws;

  int*            sortp   = (int*)           (ws + 0);
  int*            declenp = (int*)           (ws + 1024);
  int*            nactp   = (int*)           (ws + 2048);
  float*          biasp   = (float*)         (ws + 4096);
  float*          cbuf    = (float*)         (ws + 16384);
  unsigned short* hbuf    = (unsigned short*)(ws + 278528);
  unsigned short* xseq    = (unsigned short*)(ws + 540672);
  unsigned short* wihb    = (unsigned short*)(ws + 3162112);
  unsigned short* whhb    = (unsigned short*)(ws + 5259264);
  unsigned short* fcwb    = (unsigned short*)(ws + 7356416);
  // total ws use: ~17.7 MB

  k0_sort<<<1, 128, 0, stream>>>(length, captions, out, sortp, declenp, nactp);
  k1_convert<<<4096, 256, 0, stream>>>(images, captions, emb, W_ih, W_hh, b_ih, b_hh,
                                       fc_w, sortp, wihb, whhb, fcwb, biasp, xseq, hbuf, cbuf);
  for (int s = 0; s <= 20; ++s)
    step_kernel<<<348, 256, 0, stream>>>(s, xseq, wihb, whhb, fcwb, biasp, fc_b,
                                         hbuf, cbuf, nactp, out);
}

// Round 2
// 585.714 us; speedup vs baseline: 1.2077x; 1.2077x over previous
//
#include <hip/hip_runtime.h>

typedef float  f32x4 __attribute__((ext_vector_type(4)));
typedef short  s16x8 __attribute__((ext_vector_type(8)));
typedef unsigned short u16x4 __attribute__((ext_vector_type(4)));

#define MFMA16(a,b,c) __builtin_amdgcn_mfma_f32_16x16x32_bf16(a,b,c,0,0,0)

// sizes: B=128, S=20, T=19, E=H=512, G=2048, V=10000 (padded 10112)
#define PRED_ELEMS 24320000ull

__device__ __forceinline__ unsigned short f2bf(float f){
  unsigned u = __builtin_bit_cast(unsigned, f);
  u += 0x7fffu + ((u >> 16) & 1u);
  return (unsigned short)(u >> 16);
}
__device__ __forceinline__ float sigf(float x){ return 1.0f/(1.0f + __expf(-x)); }
__device__ __forceinline__ float tanh_(float x){
  x = fminf(15.0f, fmaxf(-15.0f, x));
  float e = __expf(2.0f*x);
  return (e - 1.0f) / (e + 1.0f);
}
__device__ __forceinline__ s16x8 ld8(const unsigned short* p){
  return *reinterpret_cast<const s16x8*>(p);
}

// ---------------- K0: stable descending sort by length, tail outputs ----------------
__global__ void k0_sort(const int* __restrict__ length, const int* __restrict__ captions,
                        float* __restrict__ out, int* __restrict__ sortp,
                        int* __restrict__ nactp)
{
  __shared__ int sl[128], sdl[128], ssi[128];
  int tid = threadIdx.x;
  if (tid < 128) sl[tid] = length[tid];
  __syncthreads();
  if (tid < 128){
    int l = sl[tid];
    int rank = 0;
    for (int j = 0; j < 128; ++j){
      int lj = sl[j];
      rank += (lj > l) || (lj == l && j < tid);
    }
    sortp[rank] = tid;
    ssi[rank] = tid;   sdl[rank] = l - 1;
  }
  __syncthreads();
  if (tid < 20){
    int c = 0;
    for (int r = 0; r < 128; ++r) c += (sdl[r] >= tid);
    nactp[tid] = c;
  }
  if (tid < 128){
    const size_t P = PRED_ELEMS;
    int si = ssi[tid];
    for (int t = 0; t < 20; ++t) out[P + tid*20 + t] = (float)captions[si*20 + t];
    out[P + 2560 + tid] = (float)sdl[tid];
    out[P + 2688 + tid] = (float)si;
  }
}

// ---------------- K1: bf16 conversion / gather / zero-init (4-elem units) ----------------
__device__ __forceinline__ void cvt4(unsigned short* dst, const float* src, int u){
  f32x4 v = *reinterpret_cast<const f32x4*>(src + (size_t)u*4);
  u16x4 o;
  o[0]=f2bf(v[0]); o[1]=f2bf(v[1]); o[2]=f2bf(v[2]); o[3]=f2bf(v[3]);
  *reinterpret_cast<u16x4*>(dst + (size_t)u*4) = o;
}

__global__ void k1_convert(const float* __restrict__ images, const int* __restrict__ captions,
    const float* __restrict__ emb, const float* __restrict__ wih, const float* __restrict__ whh,
    const float* __restrict__ bih, const float* __restrict__ bhh, const float* __restrict__ fcw,
    const int* __restrict__ sortp,
    unsigned short* __restrict__ wihb, unsigned short* __restrict__ whhb,
    unsigned short* __restrict__ fcwb, float* __restrict__ biasp,
    unsigned short* __restrict__ xseq, unsigned short* __restrict__ hseq,
    float* __restrict__ cbuf)
{
  const int U0 = 262144;      // W_ih  2048*512/4
  const int U1 = 262144;      // W_hh
  const int U2 = 1294336;     // fc_w padded 10112*512/4
  const int U3 = 512;         // bias 2048/4
  const int U4 = 327680;      // xseq 20*128*512/4
  const int U5 = 16384;       // hseq slot 0 (zero h_init) 128*512/4
  const int U6 = 16384;       // cbuf 128*512/4
  const int total = U0+U1+U2+U3+U4+U5+U6;
  for (int i = blockIdx.x*blockDim.x + threadIdx.x; i < total; i += gridDim.x*blockDim.x){
    int j = i;
    if (j < U0){ cvt4(wihb, wih, j); continue; }
    j -= U0;
    if (j < U1){ cvt4(whhb, whh, j); continue; }
    j -= U1;
    if (j < U2){
      int row = j >> 7;               // (j*4)/512
      if (row < 10000) cvt4(fcwb, fcw, j);
      else { u16x4 z = {0,0,0,0}; *reinterpret_cast<u16x4*>(fcwb + (size_t)j*4) = z; }
      continue;
    }
    j -= U2;
    if (j < U3){
      int e0 = j*4;
      for (int e = 0; e < 4; ++e) biasp[e0+e] = bih[e0+e] + bhh[e0+e];
      continue;
    }
    j -= U3;
    if (j < U4){
      int elem = j*4;
      int s = elem >> 16;             // /65536
      int rem = elem & 65535;
      int r = rem >> 9;
      int k = rem & 511;
      const float* src;
      if (s == 0) src = images + (size_t)sortp[r]*512 + k;
      else {
        int cap = captions[sortp[r]*20 + (s-1)];
        src = emb + (size_t)cap*512 + k;
      }
      f32x4 v = *reinterpret_cast<const f32x4*>(src);
      u16x4 o;
      o[0]=f2bf(v[0]); o[1]=f2bf(v[1]); o[2]=f2bf(v[2]); o[3]=f2bf(v[3]);
      *reinterpret_cast<u16x4*>(xseq + (size_t)j*4) = o;
      continue;
    }
    j -= U4;
    if (j < U5){ u16x4 z = {0,0,0,0}; *reinterpret_cast<u16x4*>(hseq + (size_t)j*4) = z; continue; }
    j -= U5;
    { f32x4 z = {0.f,0.f,0.f,0.f}; *reinterpret_cast<f32x4*>(cbuf + (size_t)j*4) = z; }
  }
}

// ---------------- LSTM step s: gates GEMM + cell update; h_s -> hseq slot s+1 ----------------
// grid 64 blocks: 8 row-tiles (16 rows) x 8 col-tiles (64 gate cols per gate)
__global__ __launch_bounds__(256) void lstm_step(int s,
    const unsigned short* __restrict__ xseq, const unsigned short* __restrict__ wih,
    const unsigned short* __restrict__ whh, const float* __restrict__ bias,
    unsigned short* __restrict__ hseq, float* __restrict__ cbuf,
    const int* __restrict__ nact)
{
  const int lane = threadIdx.x & 63;
  const int q    = threadIdx.x >> 6;   // gate: 0=i 1=f 2=g 3=o
  const int fr   = lane & 15;
  const int fk   = (lane >> 4) * 8;

  __shared__ float lg[4][16][65];
  int rb = blockIdx.x >> 3, cb = blockIdx.x & 7;
  int row0 = rb*16, col0 = cb*64;
  if (row0 >= nact[s]) return;

  const unsigned short* xs = xseq + (size_t)s*65536;
  const unsigned short* hp = hseq + (size_t)s*65536;       // h_{s-1}
  unsigned short*       hc = hseq + (size_t)(s+1)*65536;   // h_s

  f32x4 acc[4];
  for (int nt = 0; nt < 4; ++nt) acc[nt] = (f32x4){0.f,0.f,0.f,0.f};

  #pragma unroll 4
  for (int k0 = 0; k0 < 1024; k0 += 32){
    const unsigned short* asrc; const unsigned short* wb; int kk;
    if (k0 < 512){ asrc = xs; wb = wih; kk = k0; }
    else         { asrc = hp; wb = whh; kk = k0 - 512; }
    s16x8 a0 = ld8(asrc + (row0 + fr)*512 + kk + fk);
    int g0 = q*512 + col0 + fr;
    s16x8 b0 = ld8(wb + (g0     )*512 + kk + fk);
    s16x8 b1 = ld8(wb + (g0 + 16)*512 + kk + fk);
    s16x8 b2 = ld8(wb + (g0 + 32)*512 + kk + fk);
    s16x8 b3 = ld8(wb + (g0 + 48)*512 + kk + fk);
    acc[0] = MFMA16(a0, b0, acc[0]);
    acc[1] = MFMA16(a0, b1, acc[1]);
    acc[2] = MFMA16(a0, b2, acc[2]);
    acc[3] = MFMA16(a0, b3, acc[3]);
  }

  int rr = (lane >> 4) * 4;
  for (int nt = 0; nt < 4; ++nt)
    for (int p = 0; p < 4; ++p)
      lg[q][rr + p][nt*16 + fr] = acc[nt][p];
  __syncthreads();

  int r  = threadIdx.x >> 4;          // 0..15
  int c4 = (threadIdx.x & 15) * 4;    // 0..60
  for (int jj = 0; jj < 4; ++jj){
    int c = c4 + jj, gj = col0 + c;
    float iv = lg[0][r][c] + bias[       gj];
    float fv = lg[1][r][c] + bias[ 512 + gj];
    float gv = lg[2][r][c] + bias[1024 + gj];
    float ov = lg[3][r][c] + bias[1536 + gj];
    int idx = (row0 + r)*512 + gj;
    float cn = sigf(fv)*cbuf[idx] + sigf(iv)*tanh_(gv);
    cbuf[idx] = cn;
    hc[idx] = f2bf(sigf(ov)*tanh_(cn));
  }
}

// ---------------- batched FC: M = 19*128 rows of hseq (slots 2..20), N = 10112 ----------------
// grid (79, 19); block tile 128 rows x 128 cols; 4 waves 2x2, each 64x64
__global__ __launch_bounds__(256) void fc_kernel(
    const unsigned short* __restrict__ hseq, const unsigned short* __restrict__ fcwb,
    const float* __restrict__ fcb, const int* __restrict__ nact,
    float* __restrict__ out)
{
  const int lane = threadIdx.x & 63;
  const int wv   = threadIdx.x >> 6;
  const int wr   = wv >> 1, wc = wv & 1;
  const int fr   = lane & 15;
  const int fk   = (lane >> 4) * 8;

  const int v0 = blockIdx.x * 128;
  const int t  = blockIdx.y;
  const int n_t = nact[t + 1];

  const unsigned short* A = hseq + (size_t)(t + 2)*65536;  // h_{t+1}, 128x512

  f32x4 acc[4][4];
  for (int i = 0; i < 4; ++i)
    for (int j = 0; j < 4; ++j)
      acc[i][j] = (f32x4){0.f,0.f,0.f,0.f};

  if (wr*64 < n_t){
    #pragma unroll 2
    for (int k0 = 0; k0 < 512; k0 += 32){
      s16x8 a[4], b[4];
      for (int i = 0; i < 4; ++i)
        a[i] = ld8(A + (wr*64 + i*16 + fr)*512 + k0 + fk);
      for (int j = 0; j < 4; ++j)
        b[j] = ld8(fcwb + (size_t)(v0 + wc*64 + j*16 + fr)*512 + k0 + fk);
      for (int i = 0; i < 4; ++i)
        for (int j = 0; j < 4; ++j)
          acc[i][j] = MFMA16(a[i], b[j], acc[i][j]);
    }
  }

  const int rr = (lane >> 4) * 4;
  for (int j = 0; j < 4; ++j){
    int v = v0 + wc*64 + j*16 + fr;
    if (v >= 10000) continue;
    float bb = fcb[v];
    for (int i = 0; i < 4; ++i){
      for (int p = 0; p < 4; ++p){
        int r = wr*64 + i*16 + rr + p;
        out[(size_t)(r*19 + t)*10000 + v] = (r < n_t) ? (acc[i][j][p] + bb) : 0.0f;
      }
    }
  }
}

extern "C" void kernel_launch(void* const* d_in, const int* in_sizes, int n_in,
                              void* d_out, int out_size, void* d_ws, size_t ws_size,
                              hipStream_t stream) {
  const float* images   = (const float*)d_in[0];
  const int*   captions = (const int*)  d_in[1];
  const int*   length   = (const int*)  d_in[2];
  const float* emb      = (const float*)d_in[3];
  const float* W_ih     = (const float*)d_in[4];
  const float* W_hh     = (const float*)d_in[5];
  const float* b_ih     = (const float*)d_in[6];
  const float* b_hh     = (const float*)d_in[7];
  const float* fc_w     = (const float*)d_in[8];
  const float* fc_b     = (const float*)d_in[9];
  float* out = (float*)d_out;
  char*  ws  = (char*)d_ws;

  int*            sortp = (int*)           (ws + 0);
  int*            nactp = (int*)           (ws + 2048);
  float*          biasp = (float*)         (ws + 4096);
  float*          cbuf  = (float*)         (ws + 16384);
  unsigned short* hseq  = (unsigned short*)(ws + 278528);   // 21 slots x 128x512 bf16
  unsigned short* xseq  = (unsigned short*)(ws + 3031040);  // 20 slots
  unsigned short* wihb  = (unsigned short*)(ws + 5652480);
  unsigned short* whhb  = (unsigned short*)(ws + 7749632);
  unsigned short* fcwb  = (unsigned short*)(ws + 9846784);  // ends ~20.2 MB

  k0_sort<<<1, 128, 0, stream>>>(length, captions, out, sortp, nactp);
  k1_convert<<<4096, 256, 0, stream>>>(images, captions, emb, W_ih, W_hh, b_ih, b_hh,
                                       fc_w, sortp, wihb, whhb, fcwb, biasp, xseq, hseq, cbuf);
  for (int s = 0; s < 20; ++s)
    lstm_step<<<64, 256, 0, stream>>>(s, xseq, wihb, whhb, biasp, hseq, cbuf, nactp);
  fc_kernel<<<dim3(79, 19), 256, 0, stream>>>(hseq, fcwb, fc_b, nactp, out);
}